// Round 17
// baseline (290.753 us; speedup 1.0000x reference)
//
#include <hip/hip_runtime.h>
#include <stdint.h>

#define HID 256
#define RNUM 6
#define NNODE 40000
#define NEVENT 20000
#define NEDGE 200000
#define NKEY (NNODE*RNUM)      // 240000
#define KCAT 1792
#define EPSV 1e-5f
#define NB1 235                // ceil(NKEY/1024)
#define MAXTILES 1882          // worst-case compact rows 240896/128
#define SRCCAP (MAXTILES*128)  // 240896

typedef unsigned short u16;
typedef unsigned int u32;
typedef __attribute__((ext_vector_type(4))) float f32x4;
typedef __attribute__((ext_vector_type(4))) unsigned short u16x4;
typedef __attribute__((ext_vector_type(8))) unsigned short u16x8;
typedef __attribute__((ext_vector_type(8))) __bf16 bf16x8;

__device__ __forceinline__ float bf2f(u16 h) {
  union { u32 u; float f; } c; c.u = ((u32)h) << 16; return c.f;
}
__device__ __forceinline__ u16 f2bf(float f) {
  union { float f; u32 u; } c; c.f = f;
  return (u16)((c.u + 0x7fffu + ((c.u >> 16) & 1u)) >> 16);
}
__device__ __forceinline__ int sel6(int r, int a0, int a1, int a2, int a3, int a4, int a5) {
  int v = a0;
  v = r == 1 ? a1 : v; v = r == 2 ? a2 : v; v = r == 3 ? a3 : v;
  v = r == 4 ? a4 : v; v = r == 5 ? a5 : v;
  return v;
}

// ---------------- scan bodies (piggybacked onto big dispatches) ----------------

template <bool FLAGS>
__device__ __forceinline__ void scan1_body(const int* __restrict__ in,
                                           int* __restrict__ out,
                                           int* __restrict__ blockSums, int b) {
  __shared__ int wsum1[4];
  int t = threadIdx.x;
  int base = b * 1024 + t * 4;
  int v[4];
#pragma unroll
  for (int j = 0; j < 4; ++j) {
    int raw = (base + j < NKEY) ? in[base + j] : 0;
    v[j] = FLAGS ? (raw > 0 ? 1 : 0) : raw;
  }
  int s = v[0] + v[1] + v[2] + v[3];
  int inc = s;
  int lane = t & 63, wv = t >> 6;
#pragma unroll
  for (int d = 1; d < 64; d <<= 1) {
    int o = __shfl_up(inc, d, 64);
    if (lane >= d) inc += o;
  }
  if (lane == 63) wsum1[wv] = inc;
  __syncthreads();
  int wpre = 0;
  for (int w = 0; w < wv; ++w) wpre += wsum1[w];
  int exc = wpre + inc - s;
  int run = exc;
#pragma unroll
  for (int j = 0; j < 4; ++j) {
    if (base + j < NKEY) out[base + j] = run;
    run += v[j];
  }
  if (t == 255) blockSums[b] = wpre + inc;
}

__device__ __forceinline__ void scan2_body(const int* __restrict__ blockSums,
                                           int* __restrict__ blockOff,
                                           int nb, int* __restrict__ total_out) {
  __shared__ int wsum2[4];
  int t = threadIdx.x;
  int v = t < nb ? blockSums[t] : 0;
  int inc = v;
  int lane = t & 63, wv = t >> 6;
#pragma unroll
  for (int d = 1; d < 64; d <<= 1) {
    int o = __shfl_up(inc, d, 64);
    if (lane >= d) inc += o;
  }
  if (lane == 63) wsum2[wv] = inc;
  __syncthreads();
  int wpre = 0;
  for (int w = 0; w < wv; ++w) wpre += wsum2[w];
  if (t < nb) blockOff[t] = wpre + inc - v;
  if (t == 255) *total_out = wpre + inc;
}

__device__ __forceinline__ void scan3_body(int* __restrict__ arr,
                                           const int* __restrict__ blockOff, int b) {
  int t = threadIdx.x;
  int add = blockOff[b];
  int base = b * 1024 + t * 4;
#pragma unroll
  for (int j = 0; j < 4; ++j)
    if (base + j < NKEY) arr[base + j] += add;
}

// ---------------- fused setup: elementwise regions + LDS-tiled wall/root ----------

#define EW_R0 (NNODE*32)                 // 1,280,000 cvt quads
#define EW_R1 (EW_R0 + 4*256*128)        // +131,072 projWt
#define EW_R2 (EW_R1 + RNUM*HID + HID)   // +1,792 arel/V
#define EW_R3 (EW_R2 + NEDGE)            // +200,000 counts
#define NB_ELEM ((EW_R3 + 255) / 256)    // 6301

__global__ __launch_bounds__(256) void setup_count(
    const float* __restrict__ xe, const float* __restrict__ xf,
    const float* __restrict__ xp, const float* __restrict__ xi,
    u16* __restrict__ xbf,
    const float* __restrict__ pw, u16* __restrict__ projWt,
    const float* __restrict__ basis, const float* __restrict__ comp,
    const float* __restrict__ root, u16* __restrict__ wall,
    const float* __restrict__ ete, const float* __restrict__ emlpW,
    const float* __restrict__ emlpb,
    float* __restrict__ Arel, float* __restrict__ V,
    const int* __restrict__ e_src, const int* __restrict__ e_dst,
    const int* __restrict__ e_typ,
    int* __restrict__ cnt, int* __restrict__ cnt2) {
  __shared__ __align__(16) float Ls[8192];   // 32 KB
  int bid = blockIdx.x;
  int tid = threadIdx.x;
  if (bid >= NB_ELEM) {
    int wb = bid - NB_ELEM;
    if (wb < 192) {
      // wall einsum tile: (l, k-tile of 16, o-tile of 64), all 6 relations
      int l = wb >> 6, rem = wb & 63, kt = rem >> 2, ot = rem & 3;
#pragma unroll
      for (int i = 0; i < 32; ++i) {
        int idx = tid + i * 256;             // 8192 floats, coalesced in o
        int o = idx & 63, kk = (idx >> 6) & 15, bb = idx >> 10;
        Ls[idx] = basis[(((size_t)l * 8 + bb) * 256 + kt * 16 + kk) * 256 + ot * 64 + o];
      }
      __syncthreads();
      for (int pair = tid; pair < 384; pair += 256) {
        int r = pair >> 6, o = pair & 63;
        float c[8];
#pragma unroll
        for (int b2 = 0; b2 < 8; ++b2) c[b2] = comp[((size_t)l * 6 + r) * 8 + b2];
        u16x8 o0, o1;
#pragma unroll
        for (int kk = 0; kk < 16; ++kk) {
          float a = 0.f;
#pragma unroll
          for (int b2 = 0; b2 < 8; ++b2) a += c[b2] * Ls[b2 * 1024 + kk * 64 + o];
          if (kk < 8) o0[kk] = f2bf(a); else o1[kk - 8] = f2bf(a);
        }
        u16* wp = &wall[(size_t)l * KCAT * 256 +
                        (size_t)(r * 256 + ot * 64 + o) * 256 + kt * 16];
        *(u16x8*)wp = o0;
        *(u16x8*)(wp + 8) = o1;
      }
    } else {
      // root transpose tile: (l, k-tile of 16), all 256 o
      int rb = wb - 192;
      int l = rb >> 4, kt = rb & 15;
#pragma unroll
      for (int i = 0; i < 16; ++i) {
        int idx = tid + i * 256;             // 4096 floats, coalesced in o
        Ls[idx] = root[((size_t)l * 256 + kt * 16 + (idx >> 8)) * 256 + (idx & 255)];
      }
      __syncthreads();
      int o = tid;
      u16x8 o0, o1;
#pragma unroll
      for (int kk = 0; kk < 16; ++kk) {
        float a = Ls[kk * 256 + o];
        if (kk < 8) o0[kk] = f2bf(a); else o1[kk - 8] = f2bf(a);
      }
      u16* wp = &wall[(size_t)l * KCAT * 256 + (size_t)(1536 + o) * 256 + kt * 16];
      *(u16x8*)wp = o0;
      *(u16x8*)(wp + 8) = o1;
    }
    return;
  }
  int i = bid * 256 + tid;
  if (i < EW_R0) {
    int e = i * 4;
    int row = e >> 7, col = e & 127;
    const float* srcp; int lr;
    if (row < 20000)      { srcp = xe; lr = row; }
    else if (row < 30000) { srcp = xf; lr = row - 20000; }
    else if (row < 38000) { srcp = xp; lr = row - 30000; }
    else                  { srcp = xi; lr = row - 38000; }
    f32x4 v = *(const f32x4*)&srcp[(size_t)lr * 128 + col];
    u16x4 o = { f2bf(v[0]), f2bf(v[1]), f2bf(v[2]), f2bf(v[3]) };
    *(u16x4*)&xbf[e] = o;
  } else if (i < EW_R1) {
    int j = i - EW_R0;
    int t = j >> 15, rem = j & 32767, n = rem >> 7, k = rem & 127;
    projWt[j] = f2bf(pw[((size_t)t * 128 + k) * 256 + n]);
  } else if (i < EW_R2) {
    int j = i - EW_R1;
    if (j < RNUM * HID) {
      int r = j >> 8, c = j & 255;
      float s = emlpb[c];
#pragma unroll
      for (int k = 0; k < 16; ++k) s += ete[r * 16 + k] * emlpW[k * 256 + c];
      Arel[j] = s;
    } else {
      V[j - RNUM * HID] = emlpW[16 * 256 + (j - RNUM * HID)];
    }
  } else if (i < EW_R3) {
    int e = i - EW_R2;
    atomicAdd(&cnt[e_dst[e] * RNUM + e_typ[e]], 1);
    atomicAdd(&cnt2[e_typ[e] * NNODE + e_src[e]], 1);
  }
}

// ---------------- scan3 pair ----------------

__global__ __launch_bounds__(256) void scan3_pair(int* __restrict__ offs,
                                                  const int* __restrict__ bOff,
                                                  int* __restrict__ pos2,
                                                  const int* __restrict__ bOff2) {
  int b = blockIdx.x;
  if (b < NB1) scan3_body(offs, bOff, b);
  else         scan3_body(pos2, bOff2, b - NB1);
}

// ---------------- builder + scatter (after pos2 final) ----------------
// eInfo[pos] = {compact z row, 1/cnt(dst,rel)} packed.

__global__ void build_scatter(const int* __restrict__ cnt2, const int* __restrict__ pos2,
                              int* __restrict__ srcList, int* __restrict__ segS,
                              const int* __restrict__ e_src, const int* __restrict__ e_dst,
                              const int* __restrict__ e_typ, const float* __restrict__ e_w,
                              const int* __restrict__ offs, const int* __restrict__ cnt,
                              int* __restrict__ tmpc,
                              float* __restrict__ sW, int2* __restrict__ eInfo) {
  int i = blockIdx.x * blockDim.x + threadIdx.x;
  int S0 = 0, S1, S2, S3, S4, S5, S6;
  int a0, a1, a2, a3, a4, a5;
  {
    int c1 = pos2[1 * NNODE], c2 = pos2[2 * NNODE], c3 = pos2[3 * NNODE];
    int c4 = pos2[4 * NNODE], c5 = pos2[5 * NNODE], c6 = pos2[NKEY];
    a0 = S0 - 0;  S1 = S0 + (((c1 - 0)  + 127) & ~127);
    a1 = S1 - c1; S2 = S1 + (((c2 - c1) + 127) & ~127);
    a2 = S2 - c2; S3 = S2 + (((c3 - c2) + 127) & ~127);
    a3 = S3 - c3; S4 = S3 + (((c4 - c3) + 127) & ~127);
    a4 = S4 - c4; S5 = S4 + (((c5 - c4) + 127) & ~127);
    a5 = S5 - c5; S6 = S5 + (((c6 - c5) + 127) & ~127);
  }
  if (i == 0) {
    segS[0] = S0; segS[1] = S1; segS[2] = S2; segS[3] = S3;
    segS[4] = S4; segS[5] = S5; segS[6] = S6; segS[7] = S6 + NNODE;
  }
  if (i < NKEY) {
    if (cnt2[i] > 0) {
      int r = i / NNODE;
      int src = i - r * NNODE;
      srcList[pos2[i] + sel6(r, a0, a1, a2, a3, a4, a5)] = src;
    }
  } else if (i < NKEY + NNODE) {
    int n = i - NKEY;
    srcList[S6 + n] = n;
  } else if (i < NKEY + NNODE + NEDGE) {
    int e = i - NKEY - NNODE;
    int dst = e_dst[e], typ = e_typ[e], src = e_src[e];
    int key = dst * RNUM + typ;
    int pos = offs[key] + atomicAdd(&tmpc[key], 1);
    sW[pos] = e_w[e];
    int ci = pos2[typ * NNODE + src] + sel6(typ, a0, a1, a2, a3, a4, a5);
    float inv = 1.f / (float)cnt[key];
    union { float f; int i; } c; c.f = inv;
    eInfo[pos] = make_int2(ci, c.i);
  }
}

// ---------------- proj GEMM (type-batched, bf16 out) + piggy scan1 x2 -----------

__global__ __launch_bounds__(256) void gemm_proj(const u16* __restrict__ A,
                                                 const u16* __restrict__ Bt,
                                                 u16* __restrict__ Cv,
                                                 const int* __restrict__ cnt,
                                                 int* __restrict__ offs,
                                                 int* __restrict__ bSums,
                                                 const int* __restrict__ cnt2,
                                                 int* __restrict__ pos2,
                                                 int* __restrict__ bSums2) {
  __shared__ __align__(16) u16 lds[4][128 * 32];
  if ((int)blockIdx.x >= 630) {
    int b = (int)blockIdx.x - 630;
    if (b < NB1) scan1_body<false>(cnt, offs, bSums, b);
    else         scan1_body<true>(cnt2, pos2, bSums2, b - NB1);
    return;
  }
  int bid = blockIdx.x;
  int nt = bid & 1, ms = bid >> 1;
  int t = (ms >= 157) + (ms >= 236) + (ms >= 299);
  int cum  = t == 0 ? 0     : (t == 1 ? 157   : (t == 2 ? 236   : 299));
  int row0 = t == 0 ? 0     : (t == 1 ? 20000 : (t == 2 ? 30000 : 38000));
  int rowLim = t == 0 ? 20000 : (t == 1 ? 30000 : (t == 2 ? 38000 : 40000));
  int m0 = row0 + (ms - cum) * 128;
  int n0 = nt * 128;
  const u16* Bp = Bt + (size_t)t * 256 * 128;

  const int tid = threadIdx.x;
  const int v = tid >> 6, lane = tid & 63;
  const int wm = (v >> 1) * 64, wn = (v & 1) * 64;

  f32x4 acc[4][4];
#pragma unroll
  for (int i = 0; i < 4; ++i)
#pragma unroll
    for (int j = 0; j < 4; ++j) acc[i][j] = f32x4{0.f, 0.f, 0.f, 0.f};

  auto stage = [&](int kt, int buf) {
    const int k0 = kt << 5;
#pragma unroll
    for (int it = 0; it < 2; ++it) {
      int c = it * 256 + tid;
      int row = c >> 2, seg = c & 3;
      int sseg = seg ^ ((row >> 1) & 3);
      int ar = m0 + row; if (ar >= rowLim) ar = rowLim - 1;
      const u16* ga = A + (size_t)ar * 128 + k0 + sseg * 8;
      __builtin_amdgcn_global_load_lds(
          (const __attribute__((address_space(1))) void*)ga,
          (__attribute__((address_space(3))) void*)(&lds[buf][c * 8]),
          16, 0, 0);
      int br = n0 + row;
      const u16* gb = Bp + (size_t)br * 128 + k0 + sseg * 8;
      __builtin_amdgcn_global_load_lds(
          (const __attribute__((address_space(1))) void*)gb,
          (__attribute__((address_space(3))) void*)(&lds[2 + buf][c * 8]),
          16, 0, 0);
    }
  };

  stage(0, 0);
  for (int kt = 0; kt < 4; ++kt) {
    __syncthreads();
    if (kt + 1 < 4) stage(kt + 1, (kt + 1) & 1);
    const u16* as = &lds[kt & 1][0];
    const u16* bs = &lds[2 + (kt & 1)][0];
    const int q = lane >> 4;
    bf16x8 af[4], bfr[4];
#pragma unroll
    for (int mi = 0; mi < 4; ++mi) {
      int row = wm + mi * 16 + (lane & 15);
      int slot = q ^ ((row >> 1) & 3);
      af[mi] = *(const bf16x8*)&as[row * 32 + slot * 8];
    }
#pragma unroll
    for (int ni = 0; ni < 4; ++ni) {
      int row = wn + ni * 16 + (lane & 15);
      int slot = q ^ ((row >> 1) & 3);
      bfr[ni] = *(const bf16x8*)&bs[row * 32 + slot * 8];
    }
#pragma unroll
    for (int mi = 0; mi < 4; ++mi)
#pragma unroll
      for (int ni = 0; ni < 4; ++ni)
        acc[mi][ni] = __builtin_amdgcn_mfma_f32_16x16x32_bf16(af[mi], bfr[ni],
                                                              acc[mi][ni], 0, 0, 0);
  }

  const int rr = (lane >> 4) * 4;
  const int cc = lane & 15;
  __syncthreads();
  u16* scratch = &lds[0][0];
#pragma unroll
  for (int mi = 0; mi < 4; ++mi)
#pragma unroll
    for (int reg = 0; reg < 4; ++reg) {
      int row = wm + mi * 16 + rr + reg;
      int swz = ((row >> 2) & 3) << 4;
#pragma unroll
      for (int ni = 0; ni < 4; ++ni)
        scratch[row * 128 + ((wn + ni * 16 + cc) ^ swz)] = f2bf(acc[mi][ni][reg]);
    }
  __syncthreads();
#pragma unroll
  for (int it = 0; it < 8; ++it) {
    int row = it * 16 + (tid >> 4);
    int colr = (tid & 15) * 8;
    int grow = m0 + row;
    if (grow < rowLim) {
      int swz = ((row >> 2) & 3) << 4;
      u16x8 vv = *(const u16x8*)&scratch[row * 128 + (colr ^ swz)];
      *(u16x8*)&Cv[(size_t)grow * HID + n0 + colr] = vv;
    }
  }
}

// ---------------- compact main GEMM: zc[i] = h[srcList[i]] @ W_seg(i) ----------
// Segment-striped XCD mapping (R13, verified): per-XCD h working set ~2.6 MB.

__global__ __launch_bounds__(256) void gemm_compact(const u16* __restrict__ A,
                                                    const u16* __restrict__ Wl,
                                                    u16* __restrict__ zc,
                                                    const int* __restrict__ srcList,
                                                    const int* __restrict__ segS) {
  __shared__ __align__(16) u16 lds[4][128 * 32];
  const int nRows = segS[7];
  int bid = blockIdx.x;
  int xcd = bid & 7, slot = bid >> 3;
  int lt = slot >> 1;
  int n0 = (slot & 1) * 128;

  int mt = -1, rBase = 0, accCnt = 0;
#pragma unroll
  for (int s = 0; s < 7; ++s) {
    int sBeg = segS[s];
    int sEnd = segS[s + 1];
    int segTiles = (sEnd - sBeg + 127) >> 7;
    int cS = (segTiles + 7) >> 3;
    int beg = xcd * cS;
    int cnt = segTiles - beg;
    if (cnt < 0) cnt = 0;
    if (cnt > cS) cnt = cS;
    if (mt < 0 && lt < accCnt + cnt) {
      mt = (sBeg >> 7) + beg + (lt - accCnt);
      rBase = (s < 6) ? s * 256 : 1536;
    }
    accCnt += cnt;
  }
  if (mt < 0) return;
  int m0 = mt * 128;

  const int tid = threadIdx.x;
  const int v = tid >> 6, lane = tid & 63;
  const int wm = (v >> 1) * 64, wn = (v & 1) * 64;

  int ar0 = srcList[m0 + (tid >> 2)];
  int ar1 = srcList[m0 + 64 + (tid >> 2)];
  if ((u32)ar0 >= NNODE) ar0 = 0;
  if ((u32)ar1 >= NNODE) ar1 = 0;

  f32x4 acc[4][4];
#pragma unroll
  for (int i = 0; i < 4; ++i)
#pragma unroll
    for (int j = 0; j < 4; ++j) acc[i][j] = f32x4{0.f, 0.f, 0.f, 0.f};

  auto stage = [&](int kt, int buf) {
    const int k0 = kt << 5;
#pragma unroll
    for (int it = 0; it < 2; ++it) {
      int c = it * 256 + tid;
      int row = c >> 2, seg = c & 3;
      int sseg = seg ^ ((row >> 1) & 3);
      int ar = it == 0 ? ar0 : ar1;
      const u16* ga = A + (size_t)ar * HID + k0 + sseg * 8;
      __builtin_amdgcn_global_load_lds(
          (const __attribute__((address_space(1))) void*)ga,
          (__attribute__((address_space(3))) void*)(&lds[buf][c * 8]),
          16, 0, 0);
      int og = rBase + n0 + row;
      const u16* gb = Wl + (size_t)og * 256 + k0 + sseg * 8;
      __builtin_amdgcn_global_load_lds(
          (const __attribute__((address_space(1))) void*)gb,
          (__attribute__((address_space(3))) void*)(&lds[2 + buf][c * 8]),
          16, 0, 0);
    }
  };

  stage(0, 0);
  for (int kt = 0; kt < 8; ++kt) {       // K = 256
    __syncthreads();
    if (kt + 1 < 8) stage(kt + 1, (kt + 1) & 1);
    const u16* as = &lds[kt & 1][0];
    const u16* bs = &lds[2 + (kt & 1)][0];
    const int q = lane >> 4;
    bf16x8 af[4], bfr[4];
#pragma unroll
    for (int mi = 0; mi < 4; ++mi) {
      int row = wm + mi * 16 + (lane & 15);
      int slot2 = q ^ ((row >> 1) & 3);
      af[mi] = *(const bf16x8*)&as[row * 32 + slot2 * 8];
    }
#pragma unroll
    for (int ni = 0; ni < 4; ++ni) {
      int row = wn + ni * 16 + (lane & 15);
      int slot2 = q ^ ((row >> 1) & 3);
      bfr[ni] = *(const bf16x8*)&bs[row * 32 + slot2 * 8];
    }
#pragma unroll
    for (int mi = 0; mi < 4; ++mi)
#pragma unroll
      for (int ni = 0; ni < 4; ++ni)
        acc[mi][ni] = __builtin_amdgcn_mfma_f32_16x16x32_bf16(af[mi], bfr[ni],
                                                              acc[mi][ni], 0, 0, 0);
  }

  const int rr = (lane >> 4) * 4;
  const int cc = lane & 15;
  __syncthreads();
  u16* scratch = &lds[0][0];
#pragma unroll
  for (int mi = 0; mi < 4; ++mi)
#pragma unroll
    for (int reg = 0; reg < 4; ++reg) {
      int row = wm + mi * 16 + rr + reg;
      int swz = ((row >> 2) & 3) << 4;
#pragma unroll
      for (int ni = 0; ni < 4; ++ni)
        scratch[row * 128 + ((wn + ni * 16 + cc) ^ swz)] = f2bf(acc[mi][ni][reg]);
    }
  __syncthreads();
#pragma unroll
  for (int it = 0; it < 8; ++it) {
    int row = it * 16 + (tid >> 4);
    int colr = (tid & 15) * 8;
    int grow = m0 + row;
    if (grow < nRows) {
      int swz = ((row >> 2) & 3) << 4;
      u16x8 vv = *(const u16x8*)&scratch[row * 128 + (colr ^ swz)];
      *(u16x8*)&zc[(size_t)grow * 256 + n0 + colr] = vv;
    }
  }
}

// ---------------- proj LN (+ piggybacked scan2 x2) ----------------

__global__ __launch_bounds__(256) void ln_scan2(const u16* __restrict__ y,
                                                const float* __restrict__ pb,
                                                const float* __restrict__ pg,
                                                const float* __restrict__ pbeta,
                                                u16* __restrict__ h_bf,
                                                const int* __restrict__ bSums,
                                                int* __restrict__ bOff,
                                                int* __restrict__ tot1,
                                                const int* __restrict__ bSums2,
                                                int* __restrict__ bOff2,
                                                int* __restrict__ tot2) {
  if (blockIdx.x >= NNODE / 4) {
    if (blockIdx.x == NNODE / 4) scan2_body(bSums, bOff, NB1, tot1);
    else                         scan2_body(bSums2, bOff2, NB1, tot2);
    return;
  }
  int wid = blockIdx.x * 4 + (threadIdx.x >> 6);
  int lane = threadIdx.x & 63;
  int t = wid < 20000 ? 0 : (wid < 30000 ? 1 : (wid < 38000 ? 2 : 3));
  size_t base = (size_t)wid * HID + lane * 4;
  int pbase = t * HID + lane * 4;
  u16x4 yv = *(const u16x4*)&y[base];
  f32x4 bv0 = *(const f32x4*)&pb[pbase];
  f32x4 x;
#pragma unroll
  for (int j = 0; j < 4; ++j) x[j] = bf2f(yv[j]) + bv0[j];
  float s = x[0] + x[1] + x[2] + x[3];
  float s2 = x[0] * x[0] + x[1] * x[1] + x[2] * x[2] + x[3] * x[3];
#pragma unroll
  for (int d = 1; d < 64; d <<= 1) { s += __shfl_xor(s, d, 64); s2 += __shfl_xor(s2, d, 64); }
  float mean = s * (1.f / HID);
  float var = s2 * (1.f / HID) - mean * mean;
  float rs = rsqrtf(var + EPSV);
  f32x4 gv = *(const f32x4*)&pg[pbase];
  f32x4 bv = *(const f32x4*)&pbeta[pbase];
  u16x4 hb;
#pragma unroll
  for (int j = 0; j < 4; ++j) {
    float tv = (x[j] - mean) * rs * gv[j] + bv[j];
    tv = tv > 0.f ? tv : 0.f;
    hb[j] = f2bf(tv);
  }
  *(u16x4*)&h_bf[base] = hb;
}

// ---------------- fused aggregation + epilogue (per layer) ----------------
// two nodes per wave; eInfo-packed gather, guarded batch-4 with DEPTH-2
// eInfo software pipeline: batch k's zc loads issue from preloaded infos,
// batch k+1's eInfo loads issue before accumulation (breaks the 2-deep
// dependent chain eInfo->zc on the critical path).
// MODE 0 (layer 0): compute edge bias inline and WRITE ebias (bf16).
// MODE 1 (layers 1,2): READ precomputed ebias; skip sW/Arel/V entirely.

template <int MODE>
__global__ __launch_bounds__(256) void agg_epilogue(const u16* __restrict__ zc,
                                                    const int* __restrict__ offs,
                                                    const int2* __restrict__ eInfo,
                                                    const float* __restrict__ sortedW,
                                                    const float* __restrict__ Arel,
                                                    const float* __restrict__ V,
                                                    u16* __restrict__ ebias,
                                                    const int* __restrict__ segS,
                                                    const float* __restrict__ cb,
                                                    const float* __restrict__ g,
                                                    const float* __restrict__ b,
                                                    u16* __restrict__ h_bf,
                                                    float* __restrict__ outp) {
  int wave = (blockIdx.x * blockDim.x + threadIdx.x) >> 6;
  int lane = threadIdx.x & 63;
  int n = wave * 2 + (lane >> 5);
  if (n >= NNODE) return;
  const int col8 = (lane & 31) * 8;
  const size_t base8 = (size_t)n * HID + col8;
  const int rootS = segS[6];

  f32x4 eba = {0.f,0.f,0.f,0.f}, ebb = {0.f,0.f,0.f,0.f};
  int p0, p6;

  if constexpr (MODE == 0) {
    int bo[7];
#pragma unroll
    for (int i = 0; i < 7; ++i) bo[i] = offs[n * RNUM + i];
    p0 = bo[0]; p6 = bo[6];
    f32x4 vva = *(const f32x4*)&V[col8];
    f32x4 vvb = *(const f32x4*)&V[col8 + 4];
#pragma unroll
    for (int r = 0; r < RNUM; ++r) {
      int b0 = bo[r], b1 = bo[r + 1];
      if (b0 == b1) continue;
      f32x4 ava = *(const f32x4*)&Arel[r * HID + col8];
      f32x4 avb = *(const f32x4*)&Arel[r * HID + col8 + 4];
      for (int p = b0; p < b1; ++p) {
        float wv = sortedW[p];
#pragma unroll
        for (int j = 0; j < 4; ++j) {
          float e0 = ava[j] + wv * vva[j];
          float e1 = avb[j] + wv * vvb[j];
          eba[j] += e0 > 0.f ? e0 : 0.f;
          ebb[j] += e1 > 0.f ? e1 : 0.f;
        }
      }
    }
    int deg = p6 - p0;
    float esc = 0.1f / (float)(deg > 1 ? deg : 1);
#pragma unroll
    for (int j = 0; j < 4; ++j) { eba[j] *= esc; ebb[j] *= esc; }
    u16x8 eo;
#pragma unroll
    for (int j = 0; j < 4; ++j) { eo[j] = f2bf(eba[j]); eo[j + 4] = f2bf(ebb[j]); }
    *(u16x8*)&ebias[base8] = eo;
  } else {
    p0 = offs[n * RNUM];
    p6 = offs[n * RNUM + RNUM];
    u16x8 eb8 = *(const u16x8*)&ebias[base8];
#pragma unroll
    for (int j = 0; j < 4; ++j) { eba[j] = bf2f(eb8[j]); ebb[j] = bf2f(eb8[j + 4]); }
  }

  // gather: guarded batch-4 with depth-2 eInfo pipeline
  f32x4 xa = {0.f,0.f,0.f,0.f}, xb = {0.f,0.f,0.f,0.f};
  int2 cur0, cur1, cur2, cur3;
  {
    int m = p6 - p0; if (m > 4) m = 4;
    if (m > 0) cur0 = eInfo[p0];
    if (m > 1) cur1 = eInfo[p0 + 1];
    if (m > 2) cur2 = eInfo[p0 + 2];
    if (m > 3) cur3 = eInfo[p0 + 3];
  }
  for (int p = p0; p < p6; p += 4) {
    int m = p6 - p; if (m > 4) m = 4;
    // issue zc loads from preloaded infos
    u16x8 zv[4]; float iv[4];
#pragma unroll
    for (int t = 0; t < 4; ++t) {
      if (t < m) {
        int2 info = t == 0 ? cur0 : (t == 1 ? cur1 : (t == 2 ? cur2 : cur3));
        union { int i; float f; } c; c.i = info.y;
        iv[t] = c.f;
        zv[t] = *(const u16x8*)&zc[(size_t)info.x * 256 + col8];
      }
    }
    // prefetch next batch eInfo (independent of outstanding zc loads)
    int pn = p + 4;
    int mn = p6 - pn; if (mn > 4) mn = 4;
    if (mn > 0) cur0 = eInfo[pn];
    if (mn > 1) cur1 = eInfo[pn + 1];
    if (mn > 2) cur2 = eInfo[pn + 2];
    if (mn > 3) cur3 = eInfo[pn + 3];
    // accumulate
#pragma unroll
    for (int t = 0; t < 4; ++t) {
      if (t < m) {
#pragma unroll
        for (int j = 0; j < 4; ++j) {
          xa[j] += bf2f(zv[t][j]) * iv[t];
          xb[j] += bf2f(zv[t][j + 4]) * iv[t];
        }
      }
    }
  }

  u16x8 zr8 = *(const u16x8*)&zc[(size_t)(rootS + n) * 256 + col8];
  f32x4 cba = *(const f32x4*)&cb[col8];
  f32x4 cbb = *(const f32x4*)&cb[col8 + 4];
#pragma unroll
  for (int j = 0; j < 4; ++j) {
    xa[j] += bf2f(zr8[j])     + cba[j] + eba[j];
    xb[j] += bf2f(zr8[j + 4]) + cbb[j] + ebb[j];
  }

  float s  = xa[0]+xa[1]+xa[2]+xa[3] + xb[0]+xb[1]+xb[2]+xb[3];
  float s2 = xa[0]*xa[0]+xa[1]*xa[1]+xa[2]*xa[2]+xa[3]*xa[3]
           + xb[0]*xb[0]+xb[1]*xb[1]+xb[2]*xb[2]+xb[3]*xb[3];
#pragma unroll
  for (int d = 1; d < 32; d <<= 1) { s += __shfl_xor(s, d, 64); s2 += __shfl_xor(s2, d, 64); }
  float mean = s * (1.f / HID);
  float var = s2 * (1.f / HID) - mean * mean;
  float rs = rsqrtf(var + EPSV);

  f32x4 gva = *(const f32x4*)&g[col8];
  f32x4 gvb = *(const f32x4*)&g[col8 + 4];
  f32x4 bva = *(const f32x4*)&b[col8];
  f32x4 bvb = *(const f32x4*)&b[col8 + 4];
  u16x8 hold8 = *(const u16x8*)&h_bf[base8];
  u16x8 hb; f32x4 r0, r1;
#pragma unroll
  for (int j = 0; j < 4; ++j) {
    float tv = (xa[j] - mean) * rs * gva[j] + bva[j];
    tv = tv > 0.f ? tv : 0.f;
    r0[j] = tv + bf2f(hold8[j]);
    hb[j] = f2bf(r0[j]);
    float tw = (xb[j] - mean) * rs * gvb[j] + bvb[j];
    tw = tw > 0.f ? tw : 0.f;
    r1[j] = tw + bf2f(hold8[j + 4]);
    hb[j + 4] = f2bf(r1[j]);
  }
  *(u16x8*)&h_bf[base8] = hb;
  if (outp != nullptr && n < NEVENT) {
    *(f32x4*)&outp[base8] = r0;
    *(f32x4*)&outp[base8 + 4] = r1;
  }
}

// ---------------- launch ----------------

extern "C" void kernel_launch(void* const* d_in, const int* in_sizes, int n_in,
                              void* d_out, int out_size, void* d_ws, size_t ws_size,
                              hipStream_t stream) {
  const float* x_event = (const float*)d_in[0];
  const float* x_file  = (const float*)d_in[1];
  const float* x_proc  = (const float*)d_in[2];
  const float* x_ip    = (const float*)d_in[3];
  const int*   e_src   = (const int*)d_in[4];
  const int*   e_dst   = (const int*)d_in[5];
  const int*   e_typ   = (const int*)d_in[6];
  const float* e_w     = (const float*)d_in[7];
  const float* proj_W  = (const float*)d_in[8];
  const float* proj_b  = (const float*)d_in[9];
  const float* proj_g  = (const float*)d_in[10];
  const float* proj_be = (const float*)d_in[11];
  const float* ete     = (const float*)d_in[12];
  const float* emlpW   = (const float*)d_in[13];
  const float* emlpb   = (const float*)d_in[14];
  const float* basis   = (const float*)d_in[15];
  const float* comp    = (const float*)d_in[16];
  const float* root    = (const float*)d_in[17];
  const float* convb   = (const float*)d_in[18];
  const float* ln_g    = (const float*)d_in[19];
  const float* ln_b    = (const float*)d_in[20];
  float* outp = (float*)d_out;

  char* p = (char*)d_ws;
  auto alloc = [&](size_t bytes) {
    char* r = p; p += (bytes + 255) & ~(size_t)255; return r;
  };
  u16*   zc      = (u16*)  alloc((size_t)SRCCAP * 256 * 2);   // 123.3 MB
  u16*   h_bf    = (u16*)  alloc((size_t)NNODE * HID * 2);    // 20.5 MB
  u16*   ebias   = (u16*)  alloc((size_t)NNODE * HID * 2);    // 20.5 MB
  u16*   xbf     = (u16*)  alloc((size_t)NNODE * 128 * 2);    // 10.3 MB
  u16*   projWt  = (u16*)  alloc((size_t)4 * HID * 128 * 2);
  u16*   WallT   = (u16*)  alloc((size_t)3 * KCAT * 256 * 2);
  float* Arel    = (float*)alloc(6 * HID * 4);
  float* Vv      = (float*)alloc(HID * 4);
  int*   cnt     = (int*)  alloc(NKEY * 4);   // cnt/tmpc/cnt2 contiguous
  int*   tmpc    = (int*)  alloc(NKEY * 4);
  int*   cnt2    = (int*)  alloc(NKEY * 4);
  int*   offs    = (int*)  alloc((NKEY + 1) * 4);
  int*   pos2    = (int*)  alloc((NKEY + 1) * 4);
  int*   bSums   = (int*)  alloc(256 * 4);
  int*   bOff    = (int*)  alloc(256 * 4);
  int*   bSums2  = (int*)  alloc(256 * 4);
  int*   bOff2   = (int*)  alloc(256 * 4);
  int*   srcList = (int*)  alloc((size_t)SRCCAP * 4);
  int*   segS    = (int*)  alloc(16 * 4);
  int2*  eInfo   = (int2*) alloc((size_t)NEDGE * 8);
  float* sW      = (float*)alloc((size_t)NEDGE * 4);
  u16*   y       = zc;   // alias: proj output dead before zc written
  (void)in_sizes; (void)n_in; (void)out_size; (void)ws_size;

  // 1. zero cnt + tmpc + cnt2 (contiguous)
  hipMemsetAsync(cnt, 0, (size_t)NKEY * 12, stream);

  // 2. setup: elementwise + counts, plus LDS-tiled wall (192) + root (48) blocks
  setup_count<<<NB_ELEM + 240, 256, 0, stream>>>(
      x_event, x_file, x_proc, x_ip, xbf, proj_W, projWt,
      basis, comp, root, WallT, ete, emlpW, emlpb, Arel, Vv,
      e_src, e_dst, e_typ, cnt, cnt2);

  // 3. proj GEMM (630) + scan1(cnt->offs) + scan1f(cnt2->pos2)
  gemm_proj<<<630 + 2 * NB1, 256, 0, stream>>>(xbf, projWt, y,
                                               cnt, offs, bSums,
                                               cnt2, pos2, bSums2);

  // 4. proj LN (10000) + scan2 x2
  ln_scan2<<<NNODE / 4 + 2, 256, 0, stream>>>(y, proj_b, proj_g, proj_be, h_bf,
                                              bSums, bOff, offs + NKEY,
                                              bSums2, bOff2, pos2 + NKEY);

  // 5. scan3 for both prefix arrays
  scan3_pair<<<2 * NB1, 256, 0, stream>>>(offs, bOff, pos2, bOff2);

  // 6. builder (srcList, segS) + scatter (sW, eInfo)
  build_scatter<<<(NKEY + NNODE + NEDGE + 255) / 256, 256, 0, stream>>>(
      cnt2, pos2, srcList, segS, e_src, e_dst, e_typ, e_w, offs, cnt, tmpc,
      sW, eInfo);

  // 7. layers (grid: 8 XCDs x (nTiles/8 + 7 ceil-slack) x 2 n-tiles, worst case)
  const int nblk = 8 * ((MAXTILES + 7) / 8 + 7) * 2;   // 3888
  const int aggblk = (NNODE / 2 * 64) / 256;
  // layer 0: compute + persist edge bias
  gemm_compact<<<nblk, 256, 0, stream>>>(h_bf, WallT, zc, srcList, segS);
  agg_epilogue<0><<<aggblk, 256, 0, stream>>>(
      zc, offs, eInfo, sW, Arel, Vv, ebias, segS,
      convb, ln_g, ln_b, h_bf, nullptr);
  for (int l = 1; l < 3; ++l) {
    gemm_compact<<<nblk, 256, 0, stream>>>(
        h_bf, WallT + (size_t)l * KCAT * 256, zc, srcList, segS);
    agg_epilogue<1><<<aggblk, 256, 0, stream>>>(
        zc, offs, eInfo, sW, Arel, Vv, ebias, segS,
        convb + l * HID, ln_g + l * HID, ln_b + l * HID,
        h_bf, (l == 2) ? outp : nullptr);
  }
}

// Round 18
// 281.865 us; speedup vs baseline: 1.0315x; 1.0315x over previous
//
#include <hip/hip_runtime.h>
#include <stdint.h>

#define HID 256
#define RNUM 6
#define NNODE 40000
#define NEVENT 20000
#define NEDGE 200000
#define NKEY (NNODE*RNUM)      // 240000
#define KCAT 1792
#define EPSV 1e-5f
#define NB1 235                // ceil(NKEY/1024)
#define MAXTILES 1882          // worst-case compact rows 240896/128
#define SRCCAP (MAXTILES*128)  // 240896

typedef unsigned short u16;
typedef unsigned int u32;
typedef __attribute__((ext_vector_type(4))) float f32x4;
typedef __attribute__((ext_vector_type(4))) unsigned short u16x4;
typedef __attribute__((ext_vector_type(8))) unsigned short u16x8;
typedef __attribute__((ext_vector_type(8))) __bf16 bf16x8;

__device__ __forceinline__ float bf2f(u16 h) {
  union { u32 u; float f; } c; c.u = ((u32)h) << 16; return c.f;
}
__device__ __forceinline__ u16 f2bf(float f) {
  union { float f; u32 u; } c; c.f = f;
  return (u16)((c.u + 0x7fffu + ((c.u >> 16) & 1u)) >> 16);
}
__device__ __forceinline__ int sel6(int r, int a0, int a1, int a2, int a3, int a4, int a5) {
  int v = a0;
  v = r == 1 ? a1 : v; v = r == 2 ? a2 : v; v = r == 3 ? a3 : v;
  v = r == 4 ? a4 : v; v = r == 5 ? a5 : v;
  return v;
}

// ---------------- scan bodies (piggybacked onto big dispatches) ----------------

template <bool FLAGS>
__device__ __forceinline__ void scan1_body(const int* __restrict__ in,
                                           int* __restrict__ out,
                                           int* __restrict__ blockSums, int b) {
  __shared__ int wsum1[4];
  int t = threadIdx.x;
  int base = b * 1024 + t * 4;
  int v[4];
#pragma unroll
  for (int j = 0; j < 4; ++j) {
    int raw = (base + j < NKEY) ? in[base + j] : 0;
    v[j] = FLAGS ? (raw > 0 ? 1 : 0) : raw;
  }
  int s = v[0] + v[1] + v[2] + v[3];
  int inc = s;
  int lane = t & 63, wv = t >> 6;
#pragma unroll
  for (int d = 1; d < 64; d <<= 1) {
    int o = __shfl_up(inc, d, 64);
    if (lane >= d) inc += o;
  }
  if (lane == 63) wsum1[wv] = inc;
  __syncthreads();
  int wpre = 0;
  for (int w = 0; w < wv; ++w) wpre += wsum1[w];
  int exc = wpre + inc - s;
  int run = exc;
#pragma unroll
  for (int j = 0; j < 4; ++j) {
    if (base + j < NKEY) out[base + j] = run;
    run += v[j];
  }
  if (t == 255) blockSums[b] = wpre + inc;
}

__device__ __forceinline__ void scan2_body(const int* __restrict__ blockSums,
                                           int* __restrict__ blockOff,
                                           int nb, int* __restrict__ total_out) {
  __shared__ int wsum2[4];
  int t = threadIdx.x;
  int v = t < nb ? blockSums[t] : 0;
  int inc = v;
  int lane = t & 63, wv = t >> 6;
#pragma unroll
  for (int d = 1; d < 64; d <<= 1) {
    int o = __shfl_up(inc, d, 64);
    if (lane >= d) inc += o;
  }
  if (lane == 63) wsum2[wv] = inc;
  __syncthreads();
  int wpre = 0;
  for (int w = 0; w < wv; ++w) wpre += wsum2[w];
  if (t < nb) blockOff[t] = wpre + inc - v;
  if (t == 255) *total_out = wpre + inc;
}

__device__ __forceinline__ void scan3_body(int* __restrict__ arr,
                                           const int* __restrict__ blockOff, int b) {
  int t = threadIdx.x;
  int add = blockOff[b];
  int base = b * 1024 + t * 4;
#pragma unroll
  for (int j = 0; j < 4; ++j)
    if (base + j < NKEY) arr[base + j] += add;
}

// ---------------- fused setup: elementwise regions + LDS-tiled wall/root ----------

#define EW_R0 (NNODE*32)                 // 1,280,000 cvt quads
#define EW_R1 (EW_R0 + 4*256*128)        // +131,072 projWt
#define EW_R2 (EW_R1 + RNUM*HID + HID)   // +1,792 arel/V
#define EW_R3 (EW_R2 + NEDGE)            // +200,000 counts
#define NB_ELEM ((EW_R3 + 255) / 256)    // 6301

__global__ __launch_bounds__(256) void setup_count(
    const float* __restrict__ xe, const float* __restrict__ xf,
    const float* __restrict__ xp, const float* __restrict__ xi,
    u16* __restrict__ xbf,
    const float* __restrict__ pw, u16* __restrict__ projWt,
    const float* __restrict__ basis, const float* __restrict__ comp,
    const float* __restrict__ root, u16* __restrict__ wall,
    const float* __restrict__ ete, const float* __restrict__ emlpW,
    const float* __restrict__ emlpb,
    float* __restrict__ Arel, float* __restrict__ V,
    const int* __restrict__ e_src, const int* __restrict__ e_dst,
    const int* __restrict__ e_typ,
    int* __restrict__ cnt, int* __restrict__ cnt2) {
  __shared__ __align__(16) float Ls[8192];   // 32 KB
  int bid = blockIdx.x;
  int tid = threadIdx.x;
  if (bid >= NB_ELEM) {
    int wb = bid - NB_ELEM;
    if (wb < 192) {
      // wall einsum tile: (l, k-tile of 16, o-tile of 64), all 6 relations
      int l = wb >> 6, rem = wb & 63, kt = rem >> 2, ot = rem & 3;
#pragma unroll
      for (int i = 0; i < 32; ++i) {
        int idx = tid + i * 256;             // 8192 floats, coalesced in o
        int o = idx & 63, kk = (idx >> 6) & 15, bb = idx >> 10;
        Ls[idx] = basis[(((size_t)l * 8 + bb) * 256 + kt * 16 + kk) * 256 + ot * 64 + o];
      }
      __syncthreads();
      for (int pair = tid; pair < 384; pair += 256) {
        int r = pair >> 6, o = pair & 63;
        float c[8];
#pragma unroll
        for (int b2 = 0; b2 < 8; ++b2) c[b2] = comp[((size_t)l * 6 + r) * 8 + b2];
        u16x8 o0, o1;
#pragma unroll
        for (int kk = 0; kk < 16; ++kk) {
          float a = 0.f;
#pragma unroll
          for (int b2 = 0; b2 < 8; ++b2) a += c[b2] * Ls[b2 * 1024 + kk * 64 + o];
          if (kk < 8) o0[kk] = f2bf(a); else o1[kk - 8] = f2bf(a);
        }
        u16* wp = &wall[(size_t)l * KCAT * 256 +
                        (size_t)(r * 256 + ot * 64 + o) * 256 + kt * 16];
        *(u16x8*)wp = o0;
        *(u16x8*)(wp + 8) = o1;
      }
    } else {
      // root transpose tile: (l, k-tile of 16), all 256 o
      int rb = wb - 192;
      int l = rb >> 4, kt = rb & 15;
#pragma unroll
      for (int i = 0; i < 16; ++i) {
        int idx = tid + i * 256;             // 4096 floats, coalesced in o
        Ls[idx] = root[((size_t)l * 256 + kt * 16 + (idx >> 8)) * 256 + (idx & 255)];
      }
      __syncthreads();
      int o = tid;
      u16x8 o0, o1;
#pragma unroll
      for (int kk = 0; kk < 16; ++kk) {
        float a = Ls[kk * 256 + o];
        if (kk < 8) o0[kk] = f2bf(a); else o1[kk - 8] = f2bf(a);
      }
      u16* wp = &wall[(size_t)l * KCAT * 256 + (size_t)(1536 + o) * 256 + kt * 16];
      *(u16x8*)wp = o0;
      *(u16x8*)(wp + 8) = o1;
    }
    return;
  }
  int i = bid * 256 + tid;
  if (i < EW_R0) {
    int e = i * 4;
    int row = e >> 7, col = e & 127;
    const float* srcp; int lr;
    if (row < 20000)      { srcp = xe; lr = row; }
    else if (row < 30000) { srcp = xf; lr = row - 20000; }
    else if (row < 38000) { srcp = xp; lr = row - 30000; }
    else                  { srcp = xi; lr = row - 38000; }
    f32x4 v = *(const f32x4*)&srcp[(size_t)lr * 128 + col];
    u16x4 o = { f2bf(v[0]), f2bf(v[1]), f2bf(v[2]), f2bf(v[3]) };
    *(u16x4*)&xbf[e] = o;
  } else if (i < EW_R1) {
    int j = i - EW_R0;
    int t = j >> 15, rem = j & 32767, n = rem >> 7, k = rem & 127;
    projWt[j] = f2bf(pw[((size_t)t * 128 + k) * 256 + n]);
  } else if (i < EW_R2) {
    int j = i - EW_R1;
    if (j < RNUM * HID) {
      int r = j >> 8, c = j & 255;
      float s = emlpb[c];
#pragma unroll
      for (int k = 0; k < 16; ++k) s += ete[r * 16 + k] * emlpW[k * 256 + c];
      Arel[j] = s;
    } else {
      V[j - RNUM * HID] = emlpW[16 * 256 + (j - RNUM * HID)];
    }
  } else if (i < EW_R3) {
    int e = i - EW_R2;
    atomicAdd(&cnt[e_dst[e] * RNUM + e_typ[e]], 1);
    atomicAdd(&cnt2[e_typ[e] * NNODE + e_src[e]], 1);
  }
}

// ---------------- scan3 pair ----------------

__global__ __launch_bounds__(256) void scan3_pair(int* __restrict__ offs,
                                                  const int* __restrict__ bOff,
                                                  int* __restrict__ pos2,
                                                  const int* __restrict__ bOff2) {
  int b = blockIdx.x;
  if (b < NB1) scan3_body(offs, bOff, b);
  else         scan3_body(pos2, bOff2, b - NB1);
}

// ---------------- builder + scatter (after pos2 final) ----------------
// eInfo[pos] = {compact z row, 1/cnt(dst,rel)} packed.

__global__ void build_scatter(const int* __restrict__ cnt2, const int* __restrict__ pos2,
                              int* __restrict__ srcList, int* __restrict__ segS,
                              const int* __restrict__ e_src, const int* __restrict__ e_dst,
                              const int* __restrict__ e_typ, const float* __restrict__ e_w,
                              const int* __restrict__ offs, const int* __restrict__ cnt,
                              int* __restrict__ tmpc,
                              float* __restrict__ sW, int2* __restrict__ eInfo) {
  int i = blockIdx.x * blockDim.x + threadIdx.x;
  int S0 = 0, S1, S2, S3, S4, S5, S6;
  int a0, a1, a2, a3, a4, a5;
  {
    int c1 = pos2[1 * NNODE], c2 = pos2[2 * NNODE], c3 = pos2[3 * NNODE];
    int c4 = pos2[4 * NNODE], c5 = pos2[5 * NNODE], c6 = pos2[NKEY];
    a0 = S0 - 0;  S1 = S0 + (((c1 - 0)  + 127) & ~127);
    a1 = S1 - c1; S2 = S1 + (((c2 - c1) + 127) & ~127);
    a2 = S2 - c2; S3 = S2 + (((c3 - c2) + 127) & ~127);
    a3 = S3 - c3; S4 = S3 + (((c4 - c3) + 127) & ~127);
    a4 = S4 - c4; S5 = S4 + (((c5 - c4) + 127) & ~127);
    a5 = S5 - c5; S6 = S5 + (((c6 - c5) + 127) & ~127);
  }
  if (i == 0) {
    segS[0] = S0; segS[1] = S1; segS[2] = S2; segS[3] = S3;
    segS[4] = S4; segS[5] = S5; segS[6] = S6; segS[7] = S6 + NNODE;
  }
  if (i < NKEY) {
    if (cnt2[i] > 0) {
      int r = i / NNODE;
      int src = i - r * NNODE;
      srcList[pos2[i] + sel6(r, a0, a1, a2, a3, a4, a5)] = src;
    }
  } else if (i < NKEY + NNODE) {
    int n = i - NKEY;
    srcList[S6 + n] = n;
  } else if (i < NKEY + NNODE + NEDGE) {
    int e = i - NKEY - NNODE;
    int dst = e_dst[e], typ = e_typ[e], src = e_src[e];
    int key = dst * RNUM + typ;
    int pos = offs[key] + atomicAdd(&tmpc[key], 1);
    sW[pos] = e_w[e];
    int ci = pos2[typ * NNODE + src] + sel6(typ, a0, a1, a2, a3, a4, a5);
    float inv = 1.f / (float)cnt[key];
    union { float f; int i; } c; c.f = inv;
    eInfo[pos] = make_int2(ci, c.i);
  }
}

// ---------------- proj GEMM (type-batched, bf16 out) + piggy scan1 x2 -----------

__global__ __launch_bounds__(256) void gemm_proj(const u16* __restrict__ A,
                                                 const u16* __restrict__ Bt,
                                                 u16* __restrict__ Cv,
                                                 const int* __restrict__ cnt,
                                                 int* __restrict__ offs,
                                                 int* __restrict__ bSums,
                                                 const int* __restrict__ cnt2,
                                                 int* __restrict__ pos2,
                                                 int* __restrict__ bSums2) {
  __shared__ __align__(16) u16 lds[4][128 * 32];
  if ((int)blockIdx.x >= 630) {
    int b = (int)blockIdx.x - 630;
    if (b < NB1) scan1_body<false>(cnt, offs, bSums, b);
    else         scan1_body<true>(cnt2, pos2, bSums2, b - NB1);
    return;
  }
  int bid = blockIdx.x;
  int nt = bid & 1, ms = bid >> 1;
  int t = (ms >= 157) + (ms >= 236) + (ms >= 299);
  int cum  = t == 0 ? 0     : (t == 1 ? 157   : (t == 2 ? 236   : 299));
  int row0 = t == 0 ? 0     : (t == 1 ? 20000 : (t == 2 ? 30000 : 38000));
  int rowLim = t == 0 ? 20000 : (t == 1 ? 30000 : (t == 2 ? 38000 : 40000));
  int m0 = row0 + (ms - cum) * 128;
  int n0 = nt * 128;
  const u16* Bp = Bt + (size_t)t * 256 * 128;

  const int tid = threadIdx.x;
  const int v = tid >> 6, lane = tid & 63;
  const int wm = (v >> 1) * 64, wn = (v & 1) * 64;

  f32x4 acc[4][4];
#pragma unroll
  for (int i = 0; i < 4; ++i)
#pragma unroll
    for (int j = 0; j < 4; ++j) acc[i][j] = f32x4{0.f, 0.f, 0.f, 0.f};

  auto stage = [&](int kt, int buf) {
    const int k0 = kt << 5;
#pragma unroll
    for (int it = 0; it < 2; ++it) {
      int c = it * 256 + tid;
      int row = c >> 2, seg = c & 3;
      int sseg = seg ^ ((row >> 1) & 3);
      int ar = m0 + row; if (ar >= rowLim) ar = rowLim - 1;
      const u16* ga = A + (size_t)ar * 128 + k0 + sseg * 8;
      __builtin_amdgcn_global_load_lds(
          (const __attribute__((address_space(1))) void*)ga,
          (__attribute__((address_space(3))) void*)(&lds[buf][c * 8]),
          16, 0, 0);
      int br = n0 + row;
      const u16* gb = Bp + (size_t)br * 128 + k0 + sseg * 8;
      __builtin_amdgcn_global_load_lds(
          (const __attribute__((address_space(1))) void*)gb,
          (__attribute__((address_space(3))) void*)(&lds[2 + buf][c * 8]),
          16, 0, 0);
    }
  };

  stage(0, 0);
  for (int kt = 0; kt < 4; ++kt) {
    __syncthreads();
    if (kt + 1 < 4) stage(kt + 1, (kt + 1) & 1);
    const u16* as = &lds[kt & 1][0];
    const u16* bs = &lds[2 + (kt & 1)][0];
    const int q = lane >> 4;
    bf16x8 af[4], bfr[4];
#pragma unroll
    for (int mi = 0; mi < 4; ++mi) {
      int row = wm + mi * 16 + (lane & 15);
      int slot = q ^ ((row >> 1) & 3);
      af[mi] = *(const bf16x8*)&as[row * 32 + slot * 8];
    }
#pragma unroll
    for (int ni = 0; ni < 4; ++ni) {
      int row = wn + ni * 16 + (lane & 15);
      int slot = q ^ ((row >> 1) & 3);
      bfr[ni] = *(const bf16x8*)&bs[row * 32 + slot * 8];
    }
#pragma unroll
    for (int mi = 0; mi < 4; ++mi)
#pragma unroll
      for (int ni = 0; ni < 4; ++ni)
        acc[mi][ni] = __builtin_amdgcn_mfma_f32_16x16x32_bf16(af[mi], bfr[ni],
                                                              acc[mi][ni], 0, 0, 0);
  }

  const int rr = (lane >> 4) * 4;
  const int cc = lane & 15;
  __syncthreads();
  u16* scratch = &lds[0][0];
#pragma unroll
  for (int mi = 0; mi < 4; ++mi)
#pragma unroll
    for (int reg = 0; reg < 4; ++reg) {
      int row = wm + mi * 16 + rr + reg;
      int swz = ((row >> 2) & 3) << 4;
#pragma unroll
      for (int ni = 0; ni < 4; ++ni)
        scratch[row * 128 + ((wn + ni * 16 + cc) ^ swz)] = f2bf(acc[mi][ni][reg]);
    }
  __syncthreads();
#pragma unroll
  for (int it = 0; it < 8; ++it) {
    int row = it * 16 + (tid >> 4);
    int colr = (tid & 15) * 8;
    int grow = m0 + row;
    if (grow < rowLim) {
      int swz = ((row >> 2) & 3) << 4;
      u16x8 vv = *(const u16x8*)&scratch[row * 128 + (colr ^ swz)];
      *(u16x8*)&Cv[(size_t)grow * HID + n0 + colr] = vv;
    }
  }
}

// ---------------- compact main GEMM: zc[i] = h[srcList[i]] @ W_seg(i) ----------
// Segment-striped XCD mapping (R13, verified): per-XCD h working set ~2.6 MB.

__global__ __launch_bounds__(256) void gemm_compact(const u16* __restrict__ A,
                                                    const u16* __restrict__ Wl,
                                                    u16* __restrict__ zc,
                                                    const int* __restrict__ srcList,
                                                    const int* __restrict__ segS) {
  __shared__ __align__(16) u16 lds[4][128 * 32];
  const int nRows = segS[7];
  int bid = blockIdx.x;
  int xcd = bid & 7, slot = bid >> 3;
  int lt = slot >> 1;
  int n0 = (slot & 1) * 128;

  int mt = -1, rBase = 0, accCnt = 0;
#pragma unroll
  for (int s = 0; s < 7; ++s) {
    int sBeg = segS[s];
    int sEnd = segS[s + 1];
    int segTiles = (sEnd - sBeg + 127) >> 7;
    int cS = (segTiles + 7) >> 3;
    int beg = xcd * cS;
    int cnt = segTiles - beg;
    if (cnt < 0) cnt = 0;
    if (cnt > cS) cnt = cS;
    if (mt < 0 && lt < accCnt + cnt) {
      mt = (sBeg >> 7) + beg + (lt - accCnt);
      rBase = (s < 6) ? s * 256 : 1536;
    }
    accCnt += cnt;
  }
  if (mt < 0) return;
  int m0 = mt * 128;

  const int tid = threadIdx.x;
  const int v = tid >> 6, lane = tid & 63;
  const int wm = (v >> 1) * 64, wn = (v & 1) * 64;

  int ar0 = srcList[m0 + (tid >> 2)];
  int ar1 = srcList[m0 + 64 + (tid >> 2)];
  if ((u32)ar0 >= NNODE) ar0 = 0;
  if ((u32)ar1 >= NNODE) ar1 = 0;

  f32x4 acc[4][4];
#pragma unroll
  for (int i = 0; i < 4; ++i)
#pragma unroll
    for (int j = 0; j < 4; ++j) acc[i][j] = f32x4{0.f, 0.f, 0.f, 0.f};

  auto stage = [&](int kt, int buf) {
    const int k0 = kt << 5;
#pragma unroll
    for (int it = 0; it < 2; ++it) {
      int c = it * 256 + tid;
      int row = c >> 2, seg = c & 3;
      int sseg = seg ^ ((row >> 1) & 3);
      int ar = it == 0 ? ar0 : ar1;
      const u16* ga = A + (size_t)ar * HID + k0 + sseg * 8;
      __builtin_amdgcn_global_load_lds(
          (const __attribute__((address_space(1))) void*)ga,
          (__attribute__((address_space(3))) void*)(&lds[buf][c * 8]),
          16, 0, 0);
      int og = rBase + n0 + row;
      const u16* gb = Wl + (size_t)og * 256 + k0 + sseg * 8;
      __builtin_amdgcn_global_load_lds(
          (const __attribute__((address_space(1))) void*)gb,
          (__attribute__((address_space(3))) void*)(&lds[2 + buf][c * 8]),
          16, 0, 0);
    }
  };

  stage(0, 0);
  for (int kt = 0; kt < 8; ++kt) {       // K = 256
    __syncthreads();
    if (kt + 1 < 8) stage(kt + 1, (kt + 1) & 1);
    const u16* as = &lds[kt & 1][0];
    const u16* bs = &lds[2 + (kt & 1)][0];
    const int q = lane >> 4;
    bf16x8 af[4], bfr[4];
#pragma unroll
    for (int mi = 0; mi < 4; ++mi) {
      int row = wm + mi * 16 + (lane & 15);
      int slot2 = q ^ ((row >> 1) & 3);
      af[mi] = *(const bf16x8*)&as[row * 32 + slot2 * 8];
    }
#pragma unroll
    for (int ni = 0; ni < 4; ++ni) {
      int row = wn + ni * 16 + (lane & 15);
      int slot2 = q ^ ((row >> 1) & 3);
      bfr[ni] = *(const bf16x8*)&bs[row * 32 + slot2 * 8];
    }
#pragma unroll
    for (int mi = 0; mi < 4; ++mi)
#pragma unroll
      for (int ni = 0; ni < 4; ++ni)
        acc[mi][ni] = __builtin_amdgcn_mfma_f32_16x16x32_bf16(af[mi], bfr[ni],
                                                              acc[mi][ni], 0, 0, 0);
  }

  const int rr = (lane >> 4) * 4;
  const int cc = lane & 15;
  __syncthreads();
  u16* scratch = &lds[0][0];
#pragma unroll
  for (int mi = 0; mi < 4; ++mi)
#pragma unroll
    for (int reg = 0; reg < 4; ++reg) {
      int row = wm + mi * 16 + rr + reg;
      int swz = ((row >> 2) & 3) << 4;
#pragma unroll
      for (int ni = 0; ni < 4; ++ni)
        scratch[row * 128 + ((wn + ni * 16 + cc) ^ swz)] = f2bf(acc[mi][ni][reg]);
    }
  __syncthreads();
#pragma unroll
  for (int it = 0; it < 8; ++it) {
    int row = it * 16 + (tid >> 4);
    int colr = (tid & 15) * 8;
    int grow = m0 + row;
    if (grow < nRows) {
      int swz = ((row >> 2) & 3) << 4;
      u16x8 vv = *(const u16x8*)&scratch[row * 128 + (colr ^ swz)];
      *(u16x8*)&zc[(size_t)grow * 256 + n0 + colr] = vv;
    }
  }
}

// ---------------- proj LN (+ piggybacked scan2 x2) ----------------

__global__ __launch_bounds__(256) void ln_scan2(const u16* __restrict__ y,
                                                const float* __restrict__ pb,
                                                const float* __restrict__ pg,
                                                const float* __restrict__ pbeta,
                                                u16* __restrict__ h_bf,
                                                const int* __restrict__ bSums,
                                                int* __restrict__ bOff,
                                                int* __restrict__ tot1,
                                                const int* __restrict__ bSums2,
                                                int* __restrict__ bOff2,
                                                int* __restrict__ tot2) {
  if (blockIdx.x >= NNODE / 4) {
    if (blockIdx.x == NNODE / 4) scan2_body(bSums, bOff, NB1, tot1);
    else                         scan2_body(bSums2, bOff2, NB1, tot2);
    return;
  }
  int wid = blockIdx.x * 4 + (threadIdx.x >> 6);
  int lane = threadIdx.x & 63;
  int t = wid < 20000 ? 0 : (wid < 30000 ? 1 : (wid < 38000 ? 2 : 3));
  size_t base = (size_t)wid * HID + lane * 4;
  int pbase = t * HID + lane * 4;
  u16x4 yv = *(const u16x4*)&y[base];
  f32x4 bv0 = *(const f32x4*)&pb[pbase];
  f32x4 x;
#pragma unroll
  for (int j = 0; j < 4; ++j) x[j] = bf2f(yv[j]) + bv0[j];
  float s = x[0] + x[1] + x[2] + x[3];
  float s2 = x[0] * x[0] + x[1] * x[1] + x[2] * x[2] + x[3] * x[3];
#pragma unroll
  for (int d = 1; d < 64; d <<= 1) { s += __shfl_xor(s, d, 64); s2 += __shfl_xor(s2, d, 64); }
  float mean = s * (1.f / HID);
  float var = s2 * (1.f / HID) - mean * mean;
  float rs = rsqrtf(var + EPSV);
  f32x4 gv = *(const f32x4*)&pg[pbase];
  f32x4 bv = *(const f32x4*)&pbeta[pbase];
  u16x4 hb;
#pragma unroll
  for (int j = 0; j < 4; ++j) {
    float tv = (x[j] - mean) * rs * gv[j] + bv[j];
    tv = tv > 0.f ? tv : 0.f;
    hb[j] = f2bf(tv);
  }
  *(u16x4*)&h_bf[base] = hb;
}

// ---------------- fused aggregation + epilogue (per layer) ----------------
// two nodes per wave; eInfo-packed gather, plain guarded batch-4 (best-known:
// R15 bench 282.3us; batch-8 and depth-2 pipeline both regressed).
// MODE 0 (layer 0): compute edge bias inline and WRITE ebias (bf16).
// MODE 1 (layers 1,2): READ precomputed ebias; skip sW/Arel/V entirely.

template <int MODE>
__global__ __launch_bounds__(256) void agg_epilogue(const u16* __restrict__ zc,
                                                    const int* __restrict__ offs,
                                                    const int2* __restrict__ eInfo,
                                                    const float* __restrict__ sortedW,
                                                    const float* __restrict__ Arel,
                                                    const float* __restrict__ V,
                                                    u16* __restrict__ ebias,
                                                    const int* __restrict__ segS,
                                                    const float* __restrict__ cb,
                                                    const float* __restrict__ g,
                                                    const float* __restrict__ b,
                                                    u16* __restrict__ h_bf,
                                                    float* __restrict__ outp) {
  int wave = (blockIdx.x * blockDim.x + threadIdx.x) >> 6;
  int lane = threadIdx.x & 63;
  int n = wave * 2 + (lane >> 5);
  if (n >= NNODE) return;
  const int col8 = (lane & 31) * 8;
  const size_t base8 = (size_t)n * HID + col8;
  const int rootS = segS[6];

  f32x4 eba = {0.f,0.f,0.f,0.f}, ebb = {0.f,0.f,0.f,0.f};
  int p0, p6;

  if constexpr (MODE == 0) {
    int bo[7];
#pragma unroll
    for (int i = 0; i < 7; ++i) bo[i] = offs[n * RNUM + i];
    p0 = bo[0]; p6 = bo[6];
    f32x4 vva = *(const f32x4*)&V[col8];
    f32x4 vvb = *(const f32x4*)&V[col8 + 4];
#pragma unroll
    for (int r = 0; r < RNUM; ++r) {
      int b0 = bo[r], b1 = bo[r + 1];
      if (b0 == b1) continue;
      f32x4 ava = *(const f32x4*)&Arel[r * HID + col8];
      f32x4 avb = *(const f32x4*)&Arel[r * HID + col8 + 4];
      for (int p = b0; p < b1; ++p) {
        float wv = sortedW[p];
#pragma unroll
        for (int j = 0; j < 4; ++j) {
          float e0 = ava[j] + wv * vva[j];
          float e1 = avb[j] + wv * vvb[j];
          eba[j] += e0 > 0.f ? e0 : 0.f;
          ebb[j] += e1 > 0.f ? e1 : 0.f;
        }
      }
    }
    int deg = p6 - p0;
    float esc = 0.1f / (float)(deg > 1 ? deg : 1);
#pragma unroll
    for (int j = 0; j < 4; ++j) { eba[j] *= esc; ebb[j] *= esc; }
    u16x8 eo;
#pragma unroll
    for (int j = 0; j < 4; ++j) { eo[j] = f2bf(eba[j]); eo[j + 4] = f2bf(ebb[j]); }
    *(u16x8*)&ebias[base8] = eo;
  } else {
    p0 = offs[n * RNUM];
    p6 = offs[n * RNUM + RNUM];
    u16x8 eb8 = *(const u16x8*)&ebias[base8];
#pragma unroll
    for (int j = 0; j < 4; ++j) { eba[j] = bf2f(eb8[j]); ebb[j] = bf2f(eb8[j + 4]); }
  }

  // gather: eInfo-packed (compact row + 1/cnt), guarded batch-4, 16B per lane
  f32x4 xa = {0.f,0.f,0.f,0.f}, xb = {0.f,0.f,0.f,0.f};
  for (int p = p0; p < p6; p += 4) {
    int m = p6 - p; if (m > 4) m = 4;
    u16x8 zv[4]; float iv[4];
#pragma unroll
    for (int t = 0; t < 4; ++t) {
      if (t < m) {
        int2 info = eInfo[p + t];
        union { int i; float f; } c; c.i = info.y;
        iv[t] = c.f;
        zv[t] = *(const u16x8*)&zc[(size_t)info.x * 256 + col8];
      }
    }
#pragma unroll
    for (int t = 0; t < 4; ++t) {
      if (t < m) {
#pragma unroll
        for (int j = 0; j < 4; ++j) {
          xa[j] += bf2f(zv[t][j]) * iv[t];
          xb[j] += bf2f(zv[t][j + 4]) * iv[t];
        }
      }
    }
  }

  u16x8 zr8 = *(const u16x8*)&zc[(size_t)(rootS + n) * 256 + col8];
  f32x4 cba = *(const f32x4*)&cb[col8];
  f32x4 cbb = *(const f32x4*)&cb[col8 + 4];
#pragma unroll
  for (int j = 0; j < 4; ++j) {
    xa[j] += bf2f(zr8[j])     + cba[j] + eba[j];
    xb[j] += bf2f(zr8[j + 4]) + cbb[j] + ebb[j];
  }

  float s  = xa[0]+xa[1]+xa[2]+xa[3] + xb[0]+xb[1]+xb[2]+xb[3];
  float s2 = xa[0]*xa[0]+xa[1]*xa[1]+xa[2]*xa[2]+xa[3]*xa[3]
           + xb[0]*xb[0]+xb[1]*xb[1]+xb[2]*xb[2]+xb[3]*xb[3];
#pragma unroll
  for (int d = 1; d < 32; d <<= 1) { s += __shfl_xor(s, d, 64); s2 += __shfl_xor(s2, d, 64); }
  float mean = s * (1.f / HID);
  float var = s2 * (1.f / HID) - mean * mean;
  float rs = rsqrtf(var + EPSV);

  f32x4 gva = *(const f32x4*)&g[col8];
  f32x4 gvb = *(const f32x4*)&g[col8 + 4];
  f32x4 bva = *(const f32x4*)&b[col8];
  f32x4 bvb = *(const f32x4*)&b[col8 + 4];
  u16x8 hold8 = *(const u16x8*)&h_bf[base8];
  u16x8 hb; f32x4 r0, r1;
#pragma unroll
  for (int j = 0; j < 4; ++j) {
    float tv = (xa[j] - mean) * rs * gva[j] + bva[j];
    tv = tv > 0.f ? tv : 0.f;
    r0[j] = tv + bf2f(hold8[j]);
    hb[j] = f2bf(r0[j]);
    float tw = (xb[j] - mean) * rs * gvb[j] + bvb[j];
    tw = tw > 0.f ? tw : 0.f;
    r1[j] = tw + bf2f(hold8[j + 4]);
    hb[j + 4] = f2bf(r1[j]);
  }
  *(u16x8*)&h_bf[base8] = hb;
  if (outp != nullptr && n < NEVENT) {
    *(f32x4*)&outp[base8] = r0;
    *(f32x4*)&outp[base8 + 4] = r1;
  }
}

// ---------------- launch ----------------

extern "C" void kernel_launch(void* const* d_in, const int* in_sizes, int n_in,
                              void* d_out, int out_size, void* d_ws, size_t ws_size,
                              hipStream_t stream) {
  const float* x_event = (const float*)d_in[0];
  const float* x_file  = (const float*)d_in[1];
  const float* x_proc  = (const float*)d_in[2];
  const float* x_ip    = (const float*)d_in[3];
  const int*   e_src   = (const int*)d_in[4];
  const int*   e_dst   = (const int*)d_in[5];
  const int*   e_typ   = (const int*)d_in[6];
  const float* e_w     = (const float*)d_in[7];
  const float* proj_W  = (const float*)d_in[8];
  const float* proj_b  = (const float*)d_in[9];
  const float* proj_g  = (const float*)d_in[10];
  const float* proj_be = (const float*)d_in[11];
  const float* ete     = (const float*)d_in[12];
  const float* emlpW   = (const float*)d_in[13];
  const float* emlpb   = (const float*)d_in[14];
  const float* basis   = (const float*)d_in[15];
  const float* comp    = (const float*)d_in[16];
  const float* root    = (const float*)d_in[17];
  const float* convb   = (const float*)d_in[18];
  const float* ln_g    = (const float*)d_in[19];
  const float* ln_b    = (const float*)d_in[20];
  float* outp = (float*)d_out;

  char* p = (char*)d_ws;
  auto alloc = [&](size_t bytes) {
    char* r = p; p += (bytes + 255) & ~(size_t)255; return r;
  };
  u16*   zc      = (u16*)  alloc((size_t)SRCCAP * 256 * 2);   // 123.3 MB
  u16*   h_bf    = (u16*)  alloc((size_t)NNODE * HID * 2);    // 20.5 MB
  u16*   ebias   = (u16*)  alloc((size_t)NNODE * HID * 2);    // 20.5 MB
  u16*   xbf     = (u16*)  alloc((size_t)NNODE * 128 * 2);    // 10.3 MB
  u16*   projWt  = (u16*)  alloc((size_t)4 * HID * 128 * 2);
  u16*   WallT   = (u16*)  alloc((size_t)3 * KCAT * 256 * 2);
  float* Arel    = (float*)alloc(6 * HID * 4);
  float* Vv      = (float*)alloc(HID * 4);
  int*   cnt     = (int*)  alloc(NKEY * 4);   // cnt/tmpc/cnt2 contiguous
  int*   tmpc    = (int*)  alloc(NKEY * 4);
  int*   cnt2    = (int*)  alloc(NKEY * 4);
  int*   offs    = (int*)  alloc((NKEY + 1) * 4);
  int*   pos2    = (int*)  alloc((NKEY + 1) * 4);
  int*   bSums   = (int*)  alloc(256 * 4);
  int*   bOff    = (int*)  alloc(256 * 4);
  int*   bSums2  = (int*)  alloc(256 * 4);
  int*   bOff2   = (int*)  alloc(256 * 4);
  int*   srcList = (int*)  alloc((size_t)SRCCAP * 4);
  int*   segS    = (int*)  alloc(16 * 4);
  int2*  eInfo   = (int2*) alloc((size_t)NEDGE * 8);
  float* sW      = (float*)alloc((size_t)NEDGE * 4);
  u16*   y       = zc;   // alias: proj output dead before zc written
  (void)in_sizes; (void)n_in; (void)out_size; (void)ws_size;

  // 1. zero cnt + tmpc + cnt2 (contiguous)
  hipMemsetAsync(cnt, 0, (size_t)NKEY * 12, stream);

  // 2. setup: elementwise + counts, plus LDS-tiled wall (192) + root (48) blocks
  setup_count<<<NB_ELEM + 240, 256, 0, stream>>>(
      x_event, x_file, x_proc, x_ip, xbf, proj_W, projWt,
      basis, comp, root, WallT, ete, emlpW, emlpb, Arel, Vv,
      e_src, e_dst, e_typ, cnt, cnt2);

  // 3. proj GEMM (630) + scan1(cnt->offs) + scan1f(cnt2->pos2)
  gemm_proj<<<630 + 2 * NB1, 256, 0, stream>>>(xbf, projWt, y,
                                               cnt, offs, bSums,
                                               cnt2, pos2, bSums2);

  // 4. proj LN (10000) + scan2 x2
  ln_scan2<<<NNODE / 4 + 2, 256, 0, stream>>>(y, proj_b, proj_g, proj_be, h_bf,
                                              bSums, bOff, offs + NKEY,
                                              bSums2, bOff2, pos2 + NKEY);

  // 5. scan3 for both prefix arrays
  scan3_pair<<<2 * NB1, 256, 0, stream>>>(offs, bOff, pos2, bOff2);

  // 6. builder (srcList, segS) + scatter (sW, eInfo)
  build_scatter<<<(NKEY + NNODE + NEDGE + 255) / 256, 256, 0, stream>>>(
      cnt2, pos2, srcList, segS, e_src, e_dst, e_typ, e_w, offs, cnt, tmpc,
      sW, eInfo);

  // 7. layers (grid: 8 XCDs x (nTiles/8 + 7 ceil-slack) x 2 n-tiles, worst case)
  const int nblk = 8 * ((MAXTILES + 7) / 8 + 7) * 2;   // 3888
  const int aggblk = (NNODE / 2 * 64) / 256;
  // layer 0: compute + persist edge bias
  gemm_compact<<<nblk, 256, 0, stream>>>(h_bf, WallT, zc, srcList, segS);
  agg_epilogue<0><<<aggblk, 256, 0, stream>>>(
      zc, offs, eInfo, sW, Arel, Vv, ebias, segS,
      convb, ln_g, ln_b, h_bf, nullptr);
  for (int l = 1; l < 3; ++l) {
    gemm_compact<<<nblk, 256, 0, stream>>>(
        h_bf, WallT + (size_t)l * KCAT * 256, zc, srcList, segS);
    agg_epilogue<1><<<aggblk, 256, 0, stream>>>(
        zc, offs, eInfo, sW, Arel, Vv, ebias, segS,
        convb + l * HID, ln_g + l * HID, ln_b + l * HID,
        h_bf, (l == 2) ? outp : nullptr);
  }
}